// Round 6
// baseline (111.300 us; speedup 1.0000x reference)
//
#include <hip/hip_runtime.h>
#include <math.h>

#define NN 9216           // 96*96
#define LOG2E 1.4426950408889634f

typedef __attribute__((ext_vector_type(8))) __bf16 bf16x8;
typedef __attribute__((ext_vector_type(16))) float f32x16;
typedef __attribute__((ext_vector_type(4))) unsigned int u32x4;

#define MFMA32(a,b,c) __builtin_amdgcn_mfma_f32_32x32x16_bf16(a,b,c,0,0,0)

#if __has_builtin(__builtin_amdgcn_exp2f)
#define EXP2(x) __builtin_amdgcn_exp2f(x)
#else
#define EXP2(x) exp2f(x)
#endif

__device__ __forceinline__ bf16x8 zero8() {
    bf16x8 z;
    #pragma unroll
    for (int i = 0; i < 8; i++) z[i] = (__bf16)0.0f;
    return z;
}

__device__ __forceinline__ unsigned int pk2(float a, float b) {
    unsigned short ua = __builtin_bit_cast(unsigned short, (__bf16)a);
    unsigned short ub = __builtin_bit_cast(unsigned short, (__bf16)b);
    return (unsigned int)ua | ((unsigned int)ub << 16);
}

__device__ __forceinline__ void plane_swap(unsigned int &a, unsigned int &b) {
    asm("v_permlane32_swap_b32 %0, %1" : "+v"(a), "+v"(b));
}

__device__ __forceinline__ void cp16(void* lds, const void* g) {
    __builtin_amdgcn_global_load_lds(
        (const __attribute__((address_space(1))) unsigned int*)g,
        (__attribute__((address_space(3))) unsigned int*)lds, 16, 0, 0);
}

// Workspace layout (bytes):
#define OFF_QB 0              // [B][N][8]  bf16 (Q pre-scaled by log2e)
#define OFF_KB 294912         // [B][N][8]  bf16
#define OFF_VB 589824         // [B][64][N] bf16 (folded in place)
#define OFF_DP 2949120        // [4z][2b][N] fp32 D-partials (dead after fold; aliased by parts)
#define OFF_PARTS 2949120     // [8][B][64][N] bf16 PV partials
#define WS_NEED 21823488ULL

// ---------------- Kernel 1: QKV projections ----------------
// grid (36, 2, 4), block 256. z = V-output quarter; z==0 also does Q,K.
__global__ __launch_bounds__(256) void qkv_kernel(
    const float* __restrict__ x,
    const float* __restrict__ Wq, const float* __restrict__ bq,
    const float* __restrict__ Wk, const float* __restrict__ bk,
    const float* __restrict__ Wv, const float* __restrict__ bv,
    __bf16* __restrict__ QB, __bf16* __restrict__ KB, __bf16* __restrict__ VB)
{
    __shared__ float wvs[1024], wqs[512], wks[512], bvs[16], bqs[8], bks[8];
    int tid = threadIdx.x;
    int z = blockIdx.z, b = blockIdx.y;
    for (int i = tid; i < 1024; i += 256) wvs[i] = Wv[z*1024 + i];
    if (z == 0)
        for (int i = tid; i < 512; i += 256) { wqs[i] = Wq[i]; wks[i] = Wk[i]; }
    if (tid < 16) bvs[tid] = bv[z*16 + tid];
    if (tid < 8)  { bqs[tid] = bq[tid]; bks[tid] = bk[tid]; }
    __syncthreads();

    int n = blockIdx.x * 256 + tid;

    float xc[64];
    #pragma unroll
    for (int c = 0; c < 64; c++) xc[c] = x[((size_t)(b*64 + c))*NN + n];

    float v[16];
    #pragma unroll
    for (int o = 0; o < 16; o++) v[o] = bvs[o];
    #pragma unroll
    for (int c = 0; c < 64; c++) {
        float xv = xc[c];
        #pragma unroll
        for (int o = 0; o < 16; o++) v[o] = fmaf(wvs[o*64+c], xv, v[o]);
    }
    #pragma unroll
    for (int o = 0; o < 16; o++)
        VB[((size_t)(b*64 + z*16 + o))*NN + n] = (__bf16)v[o];

    if (z == 0) {
        float q[8], k[8];
        #pragma unroll
        for (int o = 0; o < 8; o++) { q[o] = bqs[o]; k[o] = bks[o]; }
        #pragma unroll
        for (int c = 0; c < 64; c++) {
            float xv = xc[c];
            #pragma unroll
            for (int o = 0; o < 8; o++) {
                q[o] = fmaf(wqs[o*64+c], xv, q[o]);
                k[o] = fmaf(wks[o*64+c], xv, k[o]);
            }
        }
        bf16x8 qv, kv;
        #pragma unroll
        for (int o = 0; o < 8; o++) {
            qv[o] = (__bf16)(q[o] * LOG2E);   // fold log2e: exp(E)=exp2(E')
            kv[o] = (__bf16)k[o];
        }
        *(bf16x8*)(QB + ((size_t)b*NN + n)*8) = qv;
        *(bf16x8*)(KB + ((size_t)b*NN + n)*8) = kv;
    }
}

// ---------------- Kernel 2: D-partials via 32x32x16 MFMA ----------------
// grid (288, 2, 4), block 256 (4 waves). Block owns 32 n; z+wave split m 16 ways.
__global__ __launch_bounds__(256) void stats_kernel(
    const __bf16* __restrict__ QB, const __bf16* __restrict__ KB,
    float* __restrict__ Dp)
{
    __shared__ float Dl[4][32];
    int tid = threadIdx.x;
    int lane = tid & 63, w = tid >> 6;
    int l31 = lane & 31, h = lane >> 5;
    int b = blockIdx.y, z = blockIdx.z;
    int n0 = blockIdx.x * 32;

    f32x16 Z16;
    #pragma unroll
    for (int r = 0; r < 16; r++) Z16[r] = 0.0f;

    bf16x8 kf = zero8();
    if (lane < 32)
        kf = *(const bf16x8*)(KB + ((size_t)b*NN + n0 + l31)*8);

    float Dacc[16];
    #pragma unroll
    for (int r = 0; r < 16; r++) Dacc[r] = 0.0f;

    const __bf16* Qb = QB + (size_t)b*NN*8;
    int mbase = z*2304 + w*576;
    for (int it = 0; it < 18; it++) {
        bf16x8 qf = zero8();
        if (lane < 32)
            qf = *(const bf16x8*)(Qb + (size_t)(mbase + it*32 + l31)*8);
        f32x16 e = MFMA32(kf, qf, Z16);
        #pragma unroll
        for (int r = 0; r < 16; r++) Dacc[r] += EXP2(e[r]);
    }
    #pragma unroll
    for (int r = 0; r < 16; r++) {
        #pragma unroll
        for (int mask = 1; mask < 32; mask <<= 1)
            Dacc[r] += __shfl_xor(Dacc[r], mask);
    }
    if (l31 == 0) {
        #pragma unroll
        for (int r = 0; r < 16; r++)
            Dl[w][(r&3) + 8*(r>>2) + 4*h] = Dacc[r];
    }
    __syncthreads();
    if (tid < 32)
        Dp[((size_t)(z*2 + b))*NN + n0 + tid] =
            Dl[0][tid] + Dl[1][tid] + Dl[2][tid] + Dl[3][tid];
}

// ---------------- Kernel 3: R = gamma/D; fold into V ----------------
// grid (288, 2), block 256.
__global__ __launch_bounds__(256) void fold_kernel(
    const float* __restrict__ Dp, const float* __restrict__ gamma_p,
    __bf16* __restrict__ VB)
{
    __shared__ float Rl[32];
    int tid = threadIdx.x;
    int b = blockIdx.y;
    int n0 = blockIdx.x * 32;
    if (tid < 32) {
        float d = 0.0f;
        #pragma unroll
        for (int zz = 0; zz < 4; zz++)
            d += Dp[((size_t)(zz*2 + b))*NN + n0 + tid];
        Rl[tid] = gamma_p[0] / d;
    }
    __syncthreads();

    int c = tid >> 2, j = tid & 3;
    __bf16* ptr = VB + ((size_t)(b*64 + c))*NN + n0 + j*8;
    bf16x8 vv = *(bf16x8*)ptr;
    #pragma unroll
    for (int i = 0; i < 8; i++)
        vv[i] = (__bf16)((float)vv[i] * Rl[j*8 + i]);
    *(bf16x8*)ptr = vv;
}

// ---------------- Kernel 4: out = x (atomic-fallback path only) ----------------
__global__ __launch_bounds__(256) void init_kernel(
    const float* __restrict__ x, float* __restrict__ out)
{
    int i = blockIdx.x*256 + threadIdx.x;
    ((float4*)out)[i] = ((const float4*)x)[i];
}

// ---------------- Kernel 5: fused exp2(E') + PV ----------------
// grid (144, 2, 8), block 128 (2 waves). Block: 64 m; wave: 32 m.
// Split z: 1152 n, 18 stages of 64. bf16 partial stores.
__global__ __launch_bounds__(128) void pv_kernel(
    const __bf16* __restrict__ QB, const __bf16* __restrict__ KB,
    const __bf16* __restrict__ VB, float* __restrict__ out,
    __bf16* __restrict__ parts)
{
    __shared__ __bf16 klin[2][64*8];     // 2 x 1KB
    __shared__ __bf16 vbuf[2][64*64];    // 2 x 8KB, [c][n] XOR-swizzled

    int tid = threadIdx.x;
    int lane = tid & 63, w = tid >> 6;
    int l31 = lane & 31, h = lane >> 5;
    int b = blockIdx.y, s = blockIdx.z;
    int mw = blockIdx.x * 64 + w * 32;

    f32x16 Z16;
    #pragma unroll
    for (int r = 0; r < 16; r++) Z16[r] = 0.0f;

    bf16x8 qf = zero8();
    if (lane < 32)
        qf = *(const bf16x8*)(QB + ((size_t)b*NN + mw + l31)*8);

    f32x16 acc[2];
    acc[0] = Z16; acc[1] = Z16;

// 128 threads: vbuf 8KB = 512 x 16B slots, 4 per thread; klin 1KB by wave 0.
// dest = uniform base + lane*16 (global_load_lds semantics); source pre-swizzled.
#define STAGE(bi, stq) do {                                                   \
    int n0_ = s*1152 + (stq)*64;                                              \
    _Pragma("unroll")                                                         \
    for (int i_ = 0; i_ < 4; i_++) {                                          \
        int p2_ = tid + i_*128;                                               \
        int c_ = p2_ >> 3, h7_ = p2_ & 7;                                     \
        int xc_ = h7_ ^ (c_ & 7);                                             \
        cp16((char*)vbuf[bi] + i_*2048 + w*1024,                              \
             VB + ((size_t)(b*64 + c_))*NN + n0_ + xc_*8);                    \
    }                                                                         \
    if (w == 0)                                                               \
        cp16((char*)klin[bi], KB + ((size_t)b*NN + n0_ + lane)*8);            \
} while (0)

    STAGE(0, 0);

    for (int st = 0; st < 18; st++) {
        int bi = st & 1;
        __syncthreads();
        if (st < 17) {
            if (bi == 0) STAGE(1, st+1); else STAGE(0, st+1);
        }
        const __bf16* kl = klin[bi];
        char* vb = (char*)vbuf[bi];

        // phase 1: both QK MFMAs
        bf16x8 kfr0 = zero8(), kfr1 = zero8();
        if (lane < 32) {
            kfr0 = *(const bf16x8*)(kl + l31*8);
            kfr1 = *(const bf16x8*)(kl + (32 + l31)*8);
        }
        f32x16 e0 = MFMA32(kfr0, qf, Z16);
        f32x16 e1 = MFMA32(kfr1, qf, Z16);

        // phase 2: exp + pack into PV A-fragments (in-register, T12)
        bf16x8 pa[2][2];
        #pragma unroll
        for (int nt = 0; nt < 2; nt++) {
            const f32x16& e = nt ? e1 : e0;
            float pf[16];
            #pragma unroll
            for (int r = 0; r < 16; r++) pf[r] = EXP2(e[r]);
            unsigned int u[8];
            #pragma unroll
            for (int q = 0; q < 8; q++) u[q] = pk2(pf[2*q], pf[2*q+1]);
            plane_swap(u[0], u[2]); plane_swap(u[1], u[3]);
            plane_swap(u[4], u[6]); plane_swap(u[5], u[7]);
            u32x4 t0 = {u[0], u[1], u[2], u[3]};
            u32x4 t1 = {u[4], u[5], u[6], u[7]};
            pa[nt][0] = __builtin_bit_cast(bf16x8, t0);
            pa[nt][1] = __builtin_bit_cast(bf16x8, t1);
        }

        // phase 3: PV MFMA cluster
        __builtin_amdgcn_s_setprio(1);
        #pragma unroll
        for (int nt = 0; nt < 2; nt++)
            #pragma unroll
            for (int ks = 0; ks < 2; ks++)
                #pragma unroll
                for (int ct = 0; ct < 2; ct++) {
                    int c = ct*32 + l31;
                    bf16x8 bfr = *(const bf16x8*)(vb + c*128 +
                        ((nt*64 + ks*32 + h*16) ^ ((c & 7) << 4)));
                    acc[ct] = MFMA32(pa[nt][ks], bfr, acc[ct]);
                }
        __builtin_amdgcn_s_setprio(0);
    }

    if (parts != nullptr) {
        __bf16* pp = parts + ((size_t)(s*2 + b))*64*NN;
        #pragma unroll
        for (int ct = 0; ct < 2; ct++) {
            int c = ct*32 + l31;
            __bf16* row = pp + (size_t)c*NN + mw + 4*h;
            #pragma unroll
            for (int q = 0; q < 4; q++) {
                uint2 v2;
                v2.x = pk2(acc[ct][4*q],   acc[ct][4*q+1]);
                v2.y = pk2(acc[ct][4*q+2], acc[ct][4*q+3]);
                *(uint2*)(row + q*8) = v2;
            }
        }
    } else {
        #pragma unroll
        for (int ct = 0; ct < 2; ct++) {
            int c = ct*32 + l31;
            #pragma unroll
            for (int r = 0; r < 16; r++) {
                int m = mw + (r&3) + 8*(r>>2) + 4*h;
                atomicAdd(out + ((size_t)(b*64 + c))*NN + m, (float)acc[ct][r]);
            }
        }
    }
}

// ---------------- Kernel 6: out = x + sum_s parts[s] ----------------
// grid 576, block 256; thread owns 8 consecutive floats (576*256*8 = 1179648 = out_size).
__global__ __launch_bounds__(256) void reduce_kernel(
    const float* __restrict__ x, const __bf16* __restrict__ parts,
    float* __restrict__ out)
{
    size_t f0 = ((size_t)blockIdx.x*256 + threadIdx.x) * 8;
    float o[8];
    float4 a = *(const float4*)(x + f0);
    float4 c = *(const float4*)(x + f0 + 4);
    o[0]=a.x; o[1]=a.y; o[2]=a.z; o[3]=a.w;
    o[4]=c.x; o[5]=c.y; o[6]=c.z; o[7]=c.w;
    #pragma unroll
    for (int sIdx = 0; sIdx < 8; sIdx++) {
        bf16x8 p = *(const bf16x8*)(parts + (size_t)sIdx*(128*NN) + f0);
        #pragma unroll
        for (int j = 0; j < 8; j++) o[j] += (float)p[j];
    }
    float4 r0 = make_float4(o[0],o[1],o[2],o[3]);
    float4 r1 = make_float4(o[4],o[5],o[6],o[7]);
    *(float4*)(out + f0) = r0;
    *(float4*)(out + f0 + 4) = r1;
}

extern "C" void kernel_launch(void* const* d_in, const int* in_sizes, int n_in,
                              void* d_out, int out_size, void* d_ws, size_t ws_size,
                              hipStream_t stream) {
    const float* x     = (const float*)d_in[0];
    const float* Wq    = (const float*)d_in[1];
    const float* bq    = (const float*)d_in[2];
    const float* Wk    = (const float*)d_in[3];
    const float* bk    = (const float*)d_in[4];
    const float* Wv    = (const float*)d_in[5];
    const float* bv    = (const float*)d_in[6];
    const float* gamma = (const float*)d_in[7];
    float* out = (float*)d_out;
    char* ws   = (char*)d_ws;

    __bf16* QB = (__bf16*)(ws + OFF_QB);
    __bf16* KB = (__bf16*)(ws + OFF_KB);
    __bf16* VB = (__bf16*)(ws + OFF_VB);
    float*  Dp = (float*)(ws + OFF_DP);

    qkv_kernel<<<dim3(36, 2, 4), 256, 0, stream>>>(x, Wq, bq, Wk, bk, Wv, bv, QB, KB, VB);
    stats_kernel<<<dim3(288, 2, 4), 256, 0, stream>>>(QB, KB, Dp);
    fold_kernel<<<dim3(288, 2), 256, 0, stream>>>(Dp, gamma, VB);

    if (ws_size >= WS_NEED) {
        __bf16* parts = (__bf16*)(ws + OFF_PARTS);
        pv_kernel<<<dim3(144, 2, 8), 128, 0, stream>>>(QB, KB, VB, out, parts);
        reduce_kernel<<<dim3(576), 256, 0, stream>>>(x, parts, out);
    } else {
        init_kernel<<<dim3(1152), 256, 0, stream>>>(x, out);
        pv_kernel<<<dim3(144, 2, 8), 128, 0, stream>>>(QB, KB, VB, out, nullptr);
    }
}

// Round 7
// 102.305 us; speedup vs baseline: 1.0879x; 1.0879x over previous
//
#include <hip/hip_runtime.h>
#include <math.h>

#define NN 9216           // 96*96
#define LOG2E 1.4426950408889634f

typedef __attribute__((ext_vector_type(8))) __bf16 bf16x8;
typedef __attribute__((ext_vector_type(16))) float f32x16;
typedef __attribute__((ext_vector_type(4))) unsigned int u32x4;

#define MFMA32(a,b,c) __builtin_amdgcn_mfma_f32_32x32x16_bf16(a,b,c,0,0,0)

#if __has_builtin(__builtin_amdgcn_exp2f)
#define EXP2(x) __builtin_amdgcn_exp2f(x)
#else
#define EXP2(x) exp2f(x)
#endif

__device__ __forceinline__ bf16x8 zero8() {
    bf16x8 z;
    #pragma unroll
    for (int i = 0; i < 8; i++) z[i] = (__bf16)0.0f;
    return z;
}

__device__ __forceinline__ unsigned int pk2(float a, float b) {
    unsigned short ua = __builtin_bit_cast(unsigned short, (__bf16)a);
    unsigned short ub = __builtin_bit_cast(unsigned short, (__bf16)b);
    return (unsigned int)ua | ((unsigned int)ub << 16);
}

__device__ __forceinline__ void plane_swap(unsigned int &a, unsigned int &b) {
    asm("v_permlane32_swap_b32 %0, %1" : "+v"(a), "+v"(b));
}

// Workspace layout (bytes):
#define OFF_QB 0              // [B][N][8]  bf16 (Q pre-scaled by log2e)
#define OFF_KB 294912         // [B][N][8]  bf16
#define OFF_VB 589824         // [B][64][N] bf16 (raw V, unfolded)
#define OFF_VF 2949120        // [B][144 tiles][8 chunks][64 lanes][8] bf16, fragment-ordered folded V
#define OFF_DP 5308416        // [4z][2b][N] fp32 D-partials
#define OFF_PARTS 5308416     // [8][B][64][N] bf16 PV partials (aliases Dp; Dp dead before pv)
#define WS_NEED 24182784ULL

// ---------------- Kernel 1: QKV projections ----------------
// grid (36, 2, 9), block 256. z==0: Q,K. z=1..8: V channels (z-1)*8..+8.
__global__ __launch_bounds__(256) void qkv_kernel(
    const float* __restrict__ x,
    const float* __restrict__ Wq, const float* __restrict__ bq,
    const float* __restrict__ Wk, const float* __restrict__ bk,
    const float* __restrict__ Wv, const float* __restrict__ bv,
    __bf16* __restrict__ QB, __bf16* __restrict__ KB, __bf16* __restrict__ VB)
{
    __shared__ float wsh[1024], bsh[16];
    int tid = threadIdx.x;
    int z = blockIdx.z, b = blockIdx.y;
    if (z == 0) {
        for (int i = tid; i < 512; i += 256) { wsh[i] = Wq[i]; wsh[512+i] = Wk[i]; }
        if (tid < 8)  { bsh[tid] = bq[tid]; bsh[8+tid] = bk[tid]; }
    } else {
        for (int i = tid; i < 512; i += 256) wsh[i] = Wv[(z-1)*512 + i];
        if (tid < 8)  bsh[tid] = bv[(z-1)*8 + tid];
    }
    __syncthreads();

    int n = blockIdx.x * 256 + tid;

    float xc[64];
    #pragma unroll
    for (int c = 0; c < 64; c++) xc[c] = x[((size_t)(b*64 + c))*NN + n];

    if (z == 0) {
        float q[8], k[8];
        #pragma unroll
        for (int o = 0; o < 8; o++) { q[o] = bsh[o]; k[o] = bsh[8+o]; }
        #pragma unroll
        for (int c = 0; c < 64; c++) {
            float xv = xc[c];
            #pragma unroll
            for (int o = 0; o < 8; o++) {
                q[o] = fmaf(wsh[o*64+c], xv, q[o]);
                k[o] = fmaf(wsh[512+o*64+c], xv, k[o]);
            }
        }
        bf16x8 qv, kv;
        #pragma unroll
        for (int o = 0; o < 8; o++) {
            qv[o] = (__bf16)(q[o] * LOG2E);   // fold log2e: exp(E)=exp2(E')
            kv[o] = (__bf16)k[o];
        }
        *(bf16x8*)(QB + ((size_t)b*NN + n)*8) = qv;
        *(bf16x8*)(KB + ((size_t)b*NN + n)*8) = kv;
    } else {
        float v[8];
        #pragma unroll
        for (int o = 0; o < 8; o++) v[o] = bsh[o];
        #pragma unroll
        for (int c = 0; c < 64; c++) {
            float xv = xc[c];
            #pragma unroll
            for (int o = 0; o < 8; o++) v[o] = fmaf(wsh[o*64+c], xv, v[o]);
        }
        #pragma unroll
        for (int o = 0; o < 8; o++)
            VB[((size_t)(b*64 + (z-1)*8 + o))*NN + n] = (__bf16)v[o];
    }
}

// ---------------- Kernel 2: D-partials via 32x32x16 MFMA ----------------
// grid (288, 2, 4), block 256 (4 waves). Block owns 32 n; z+wave split m 16 ways.
__global__ __launch_bounds__(256) void stats_kernel(
    const __bf16* __restrict__ QB, const __bf16* __restrict__ KB,
    float* __restrict__ Dp)
{
    __shared__ float Dl[4][32];
    int tid = threadIdx.x;
    int lane = tid & 63, w = tid >> 6;
    int l31 = lane & 31, h = lane >> 5;
    int b = blockIdx.y, z = blockIdx.z;
    int n0 = blockIdx.x * 32;

    f32x16 Z16;
    #pragma unroll
    for (int r = 0; r < 16; r++) Z16[r] = 0.0f;

    bf16x8 kf = zero8();
    if (lane < 32)
        kf = *(const bf16x8*)(KB + ((size_t)b*NN + n0 + l31)*8);

    float Dacc[16];
    #pragma unroll
    for (int r = 0; r < 16; r++) Dacc[r] = 0.0f;

    const __bf16* Qb = QB + (size_t)b*NN*8;
    int mbase = z*2304 + w*576;
    for (int it = 0; it < 18; it++) {
        bf16x8 qf = zero8();
        if (lane < 32)
            qf = *(const bf16x8*)(Qb + (size_t)(mbase + it*32 + l31)*8);
        f32x16 e = MFMA32(kf, qf, Z16);
        #pragma unroll
        for (int r = 0; r < 16; r++) Dacc[r] += EXP2(e[r]);
    }
    #pragma unroll
    for (int r = 0; r < 16; r++) {
        #pragma unroll
        for (int mask = 1; mask < 32; mask <<= 1)
            Dacc[r] += __shfl_xor(Dacc[r], mask);
    }
    if (l31 == 0) {
        #pragma unroll
        for (int r = 0; r < 16; r++)
            Dl[w][(r&3) + 8*(r>>2) + 4*h] = Dacc[r];
    }
    __syncthreads();
    if (tid < 32)
        Dp[((size_t)(z*2 + b))*NN + n0 + tid] =
            Dl[0][tid] + Dl[1][tid] + Dl[2][tid] + Dl[3][tid];
}

// ---------------- Kernel 3: build fragment-ordered folded VF ----------------
// grid (144, 2), block 256. Tile tg = 64 n. chunk = nt*4+ks*2+ct.
// VF element addr: ((b*144+tg)*8 + chunk)*512 + lane*8; holds
// V''[c = (chunk&1)*32 + (lane&31)][n0 + (chunk>>2)*32 + ((chunk>>1)&1)*16 + (lane>>5)*8 .. +7]
__global__ __launch_bounds__(256) void foldvf_kernel(
    const float* __restrict__ Dp, const float* __restrict__ gamma_p,
    const __bf16* __restrict__ VB, __bf16* __restrict__ VF)
{
    __shared__ float Rl[64];
    int tid = threadIdx.x;
    int b = blockIdx.y, tg = blockIdx.x;
    int n0 = tg * 64;
    if (tid < 64) {
        float d = 0.0f;
        #pragma unroll
        for (int zz = 0; zz < 4; zz++)
            d += Dp[((size_t)(zz*2 + b))*NN + n0 + tid];
        Rl[tid] = gamma_p[0] / d;
    }
    __syncthreads();

    #pragma unroll
    for (int i = 0; i < 2; i++) {
        int p = tid + i*256;               // 0..511
        int chunk = p >> 6, lane = p & 63;
        int c  = (chunk & 1)*32 + (lane & 31);
        int nl = ((chunk >> 2) & 1)*32 + ((chunk >> 1) & 1)*16 + (lane >> 5)*8;
        bf16x8 v = *(const bf16x8*)(VB + ((size_t)(b*64 + c))*NN + n0 + nl);
        bf16x8 ov;
        #pragma unroll
        for (int j = 0; j < 8; j++)
            ov[j] = (__bf16)((float)v[j] * Rl[nl + j]);
        *(bf16x8*)(VF + (((size_t)(b*144 + tg))*8 + chunk)*512 + lane*8) = ov;
    }
}

// ---------------- Kernel 4: out = x (atomic-fallback path only) ----------------
__global__ __launch_bounds__(256) void init_kernel(
    const float* __restrict__ x, float* __restrict__ out)
{
    int i = blockIdx.x*256 + threadIdx.x;
    ((float4*)out)[i] = ((const float4*)x)[i];
}

// ---------------- Kernel 5: fused exp2(E') + PV, LDS-free, barrier-free ----------------
// grid (72, 2, 8), block 256 (4 independent waves). Wave: 32 m. Split z: 1152 n, 18 tiles of 64.
// All operands register-direct from L2 (K coalesced per-lane; V via fragment-ordered VF).
__global__ __launch_bounds__(256) void pv_kernel(
    const __bf16* __restrict__ QB, const __bf16* __restrict__ KB,
    const __bf16* __restrict__ VF, float* __restrict__ out,
    __bf16* __restrict__ parts)
{
    int tid = threadIdx.x;
    int lane = tid & 63, w = tid >> 6;
    int l31 = lane & 31, h = lane >> 5;
    int b = blockIdx.y, s = blockIdx.z;
    int mw = blockIdx.x * 128 + w * 32;

    f32x16 Z16;
    #pragma unroll
    for (int r = 0; r < 16; r++) Z16[r] = 0.0f;

    bf16x8 qf = zero8();
    if (lane < 32)
        qf = *(const bf16x8*)(QB + ((size_t)b*NN + mw + l31)*8);

    f32x16 acc[2];
    acc[0] = Z16; acc[1] = Z16;

    const __bf16* kbase = KB + ((size_t)b*NN + s*1152)*8;   // + t*512 + row*8
    const __bf16* vbase = VF + ((size_t)(b*144 + s*18))*8*512;  // + t*4096 + chunk*512 + lane*8

    // prologue: tile 0 K + VF into registers
    bf16x8 kc0 = zero8(), kc1 = zero8(), kn0 = zero8(), kn1 = zero8();
    if (lane < 32) {
        kc0 = *(const bf16x8*)(kbase + l31*8);
        kc1 = *(const bf16x8*)(kbase + (32 + l31)*8);
    }
    bf16x8 vf0, vf1, vf2, vf3, vf4, vf5, vf6, vf7;
    {
        const __bf16* vp = vbase + lane*8;
        vf0 = *(const bf16x8*)(vp + 0*512); vf1 = *(const bf16x8*)(vp + 1*512);
        vf2 = *(const bf16x8*)(vp + 2*512); vf3 = *(const bf16x8*)(vp + 3*512);
        vf4 = *(const bf16x8*)(vp + 4*512); vf5 = *(const bf16x8*)(vp + 5*512);
        vf6 = *(const bf16x8*)(vp + 6*512); vf7 = *(const bf16x8*)(vp + 7*512);
    }

    for (int t = 0; t < 18; t++) {
        // QK for tile t (kc loaded one iteration ahead)
        f32x16 e0 = MFMA32(kc0, qf, Z16);
        f32x16 e1 = MFMA32(kc1, qf, Z16);

        // prefetch next K (latency covered by rest of this iteration)
        if (t < 17) {
            const __bf16* knp = kbase + (t+1)*512;
            if (lane < 32) {
                kn0 = *(const bf16x8*)(knp + l31*8);
                kn1 = *(const bf16x8*)(knp + (32 + l31)*8);
            }
        }

        // exp + pack into PV A-fragments (in-register, T12)
        bf16x8 pa[2][2];
        #pragma unroll
        for (int nt = 0; nt < 2; nt++) {
            const f32x16& e = nt ? e1 : e0;
            float pf[16];
            #pragma unroll
            for (int r = 0; r < 16; r++) pf[r] = EXP2(e[r]);
            unsigned int u[8];
            #pragma unroll
            for (int q = 0; q < 8; q++) u[q] = pk2(pf[2*q], pf[2*q+1]);
            plane_swap(u[0], u[2]); plane_swap(u[1], u[3]);
            plane_swap(u[4], u[6]); plane_swap(u[5], u[7]);
            u32x4 t0 = {u[0], u[1], u[2], u[3]};
            u32x4 t1 = {u[4], u[5], u[6], u[7]};
            pa[nt][0] = __builtin_bit_cast(bf16x8, t0);
            pa[nt][1] = __builtin_bit_cast(bf16x8, t1);
        }

        // PV MFMA cluster: chunk = nt*4 + ks*2 + ct
        __builtin_amdgcn_s_setprio(1);
        acc[0] = MFMA32(pa[0][0], vf0, acc[0]);
        acc[1] = MFMA32(pa[0][0], vf1, acc[1]);
        acc[0] = MFMA32(pa[0][1], vf2, acc[0]);
        acc[1] = MFMA32(pa[0][1], vf3, acc[1]);
        acc[0] = MFMA32(pa[1][0], vf4, acc[0]);
        acc[1] = MFMA32(pa[1][0], vf5, acc[1]);
        acc[0] = MFMA32(pa[1][1], vf6, acc[0]);
        acc[1] = MFMA32(pa[1][1], vf7, acc[1]);
        __builtin_amdgcn_s_setprio(0);

        // issue next VF loads (after PV reads; WAR-safe by in-order issue)
        if (t < 17) {
            const __bf16* vp = vbase + (t+1)*4096 + lane*8;
            vf0 = *(const bf16x8*)(vp + 0*512); vf1 = *(const bf16x8*)(vp + 1*512);
            vf2 = *(const bf16x8*)(vp + 2*512); vf3 = *(const bf16x8*)(vp + 3*512);
            vf4 = *(const bf16x8*)(vp + 4*512); vf5 = *(const bf16x8*)(vp + 5*512);
            vf6 = *(const bf16x8*)(vp + 6*512); vf7 = *(const bf16x8*)(vp + 7*512);
        }
        kc0 = kn0; kc1 = kn1;
    }

    if (parts != nullptr) {
        __bf16* pp = parts + ((size_t)(s*2 + b))*64*NN;
        #pragma unroll
        for (int ct = 0; ct < 2; ct++) {
            int c = ct*32 + l31;
            __bf16* row = pp + (size_t)c*NN + mw + 4*h;
            #pragma unroll
            for (int q = 0; q < 4; q++) {
                uint2 v2;
                v2.x = pk2(acc[ct][4*q],   acc[ct][4*q+1]);
                v2.y = pk2(acc[ct][4*q+2], acc[ct][4*q+3]);
                *(uint2*)(row + q*8) = v2;
            }
        }
    } else {
        #pragma unroll
        for (int ct = 0; ct < 2; ct++) {
            int c = ct*32 + l31;
            #pragma unroll
            for (int r = 0; r < 16; r++) {
                int m = mw + (r&3) + 8*(r>>2) + 4*h;
                atomicAdd(out + ((size_t)(b*64 + c))*NN + m, (float)acc[ct][r]);
            }
        }
    }
}

// ---------------- Kernel 6: out = x + sum_s parts[s] ----------------
// grid 576, block 256; thread owns 8 consecutive floats (576*256*8 = 1179648 = out_size).
__global__ __launch_bounds__(256) void reduce_kernel(
    const float* __restrict__ x, const __bf16* __restrict__ parts,
    float* __restrict__ out)
{
    size_t f0 = ((size_t)blockIdx.x*256 + threadIdx.x) * 8;
    float o[8];
    float4 a = *(const float4*)(x + f0);
    float4 c = *(const float4*)(x + f0 + 4);
    o[0]=a.x; o[1]=a.y; o[2]=a.z; o[3]=a.w;
    o[4]=c.x; o[5]=c.y; o[6]=c.z; o[7]=c.w;
    #pragma unroll
    for (int sIdx = 0; sIdx < 8; sIdx++) {
        bf16x8 p = *(const bf16x8*)(parts + (size_t)sIdx*(128*NN) + f0);
        #pragma unroll
        for (int j = 0; j < 8; j++) o[j] += (float)p[j];
    }
    float4 r0 = make_float4(o[0],o[1],o[2],o[3]);
    float4 r1 = make_float4(o[4],o[5],o[6],o[7]);
    *(float4*)(out + f0) = r0;
    *(float4*)(out + f0 + 4) = r1;
}

extern "C" void kernel_launch(void* const* d_in, const int* in_sizes, int n_in,
                              void* d_out, int out_size, void* d_ws, size_t ws_size,
                              hipStream_t stream) {
    const float* x     = (const float*)d_in[0];
    const float* Wq    = (const float*)d_in[1];
    const float* bq    = (const float*)d_in[2];
    const float* Wk    = (const float*)d_in[3];
    const float* bk    = (const float*)d_in[4];
    const float* Wv    = (const float*)d_in[5];
    const float* bv    = (const float*)d_in[6];
    const float* gamma = (const float*)d_in[7];
    float* out = (float*)d_out;
    char* ws   = (char*)d_ws;

    __bf16* QB = (__bf16*)(ws + OFF_QB);
    __bf16* KB = (__bf16*)(ws + OFF_KB);
    __bf16* VB = (__bf16*)(ws + OFF_VB);
    __bf16* VF = (__bf16*)(ws + OFF_VF);
    float*  Dp = (float*)(ws + OFF_DP);

    qkv_kernel<<<dim3(36, 2, 9), 256, 0, stream>>>(x, Wq, bq, Wk, bk, Wv, bv, QB, KB, VB);
    stats_kernel<<<dim3(288, 2, 4), 256, 0, stream>>>(QB, KB, Dp);
    foldvf_kernel<<<dim3(144, 2), 256, 0, stream>>>(Dp, gamma, VB, VF);

    if (ws_size >= WS_NEED) {
        __bf16* parts = (__bf16*)(ws + OFF_PARTS);
        pv_kernel<<<dim3(72, 2, 8), 256, 0, stream>>>(QB, KB, VF, out, parts);
        reduce_kernel<<<dim3(576), 256, 0, stream>>>(x, parts, out);
    } else {
        init_kernel<<<dim3(1152), 256, 0, stream>>>(x, out);
        pv_kernel<<<dim3(72, 2, 8), 256, 0, stream>>>(QB, KB, VF, out, nullptr);
    }
}

// Round 8
// 101.300 us; speedup vs baseline: 1.0987x; 1.0099x over previous
//
#include <hip/hip_runtime.h>
#include <math.h>

#define NN 9216           // 96*96
#define LOG2E 1.4426950408889634f

typedef __attribute__((ext_vector_type(8))) __bf16 bf16x8;
typedef __attribute__((ext_vector_type(16))) float f32x16;
typedef __attribute__((ext_vector_type(4))) unsigned int u32x4;

#define MFMA32(a,b,c) __builtin_amdgcn_mfma_f32_32x32x16_bf16(a,b,c,0,0,0)

#if __has_builtin(__builtin_amdgcn_exp2f)
#define EXP2(x) __builtin_amdgcn_exp2f(x)
#else
#define EXP2(x) exp2f(x)
#endif

__device__ __forceinline__ bf16x8 zero8() {
    bf16x8 z;
    #pragma unroll
    for (int i = 0; i < 8; i++) z[i] = (__bf16)0.0f;
    return z;
}

__device__ __forceinline__ unsigned int pk2(float a, float b) {
    unsigned short ua = __builtin_bit_cast(unsigned short, (__bf16)a);
    unsigned short ub = __builtin_bit_cast(unsigned short, (__bf16)b);
    return (unsigned int)ua | ((unsigned int)ub << 16);
}

__device__ __forceinline__ void plane_swap(unsigned int &a, unsigned int &b) {
    asm("v_permlane32_swap_b32 %0, %1" : "+v"(a), "+v"(b));
}

__device__ __forceinline__ void cp16(void* lds, const void* g) {
    __builtin_amdgcn_global_load_lds(
        (const __attribute__((address_space(1))) unsigned int*)g,
        (__attribute__((address_space(3))) unsigned int*)lds, 16, 0, 0);
}

// Workspace layout (bytes):
#define OFF_QB 0              // [B][N][8]  bf16 (Q pre-scaled by log2e)
#define OFF_KB 294912         // [B][N][8]  bf16
#define OFF_VB 589824         // [B][64][N] bf16 (raw V, unfolded)
#define OFF_VF 2949120        // [B][144 tiles][8 chunks][64 lanes][8] bf16, fragment-ordered folded V
#define OFF_DP 5308416        // [4z][2b][N] fp32 D-partials
#define OFF_PARTS 5308416     // [8][B][64][N] bf16 PV partials (aliases Dp; Dp dead before pv)
#define WS_NEED 24182784ULL

// ---------------- Kernel 1: QKV projections ----------------
// grid (36, 2, 9), block 256. z==0: Q,K. z=1..8: V channels (z-1)*8..+8.
__global__ __launch_bounds__(256) void qkv_kernel(
    const float* __restrict__ x,
    const float* __restrict__ Wq, const float* __restrict__ bq,
    const float* __restrict__ Wk, const float* __restrict__ bk,
    const float* __restrict__ Wv, const float* __restrict__ bv,
    __bf16* __restrict__ QB, __bf16* __restrict__ KB, __bf16* __restrict__ VB)
{
    __shared__ float wsh[1024], bsh[16];
    int tid = threadIdx.x;
    int z = blockIdx.z, b = blockIdx.y;
    if (z == 0) {
        for (int i = tid; i < 512; i += 256) { wsh[i] = Wq[i]; wsh[512+i] = Wk[i]; }
        if (tid < 8)  { bsh[tid] = bq[tid]; bsh[8+tid] = bk[tid]; }
    } else {
        for (int i = tid; i < 512; i += 256) wsh[i] = Wv[(z-1)*512 + i];
        if (tid < 8)  bsh[tid] = bv[(z-1)*8 + tid];
    }
    __syncthreads();

    int n = blockIdx.x * 256 + tid;

    float xc[64];
    #pragma unroll
    for (int c = 0; c < 64; c++) xc[c] = x[((size_t)(b*64 + c))*NN + n];

    if (z == 0) {
        float q[8], k[8];
        #pragma unroll
        for (int o = 0; o < 8; o++) { q[o] = bsh[o]; k[o] = bsh[8+o]; }
        #pragma unroll
        for (int c = 0; c < 64; c++) {
            float xv = xc[c];
            #pragma unroll
            for (int o = 0; o < 8; o++) {
                q[o] = fmaf(wsh[o*64+c], xv, q[o]);
                k[o] = fmaf(wsh[512+o*64+c], xv, k[o]);
            }
        }
        bf16x8 qv, kv;
        #pragma unroll
        for (int o = 0; o < 8; o++) {
            qv[o] = (__bf16)(q[o] * LOG2E);   // fold log2e: exp(E)=exp2(E')
            kv[o] = (__bf16)k[o];
        }
        *(bf16x8*)(QB + ((size_t)b*NN + n)*8) = qv;
        *(bf16x8*)(KB + ((size_t)b*NN + n)*8) = kv;
    } else {
        float v[8];
        #pragma unroll
        for (int o = 0; o < 8; o++) v[o] = bsh[o];
        #pragma unroll
        for (int c = 0; c < 64; c++) {
            float xv = xc[c];
            #pragma unroll
            for (int o = 0; o < 8; o++) v[o] = fmaf(wsh[o*64+c], xv, v[o]);
        }
        #pragma unroll
        for (int o = 0; o < 8; o++)
            VB[((size_t)(b*64 + (z-1)*8 + o))*NN + n] = (__bf16)v[o];
    }
}

// ---------------- Kernel 2: D-partials via 32x32x16 MFMA ----------------
// grid (288, 2, 4), block 256 (4 waves). Block owns 32 n; z+wave split m 16 ways.
__global__ __launch_bounds__(256) void stats_kernel(
    const __bf16* __restrict__ QB, const __bf16* __restrict__ KB,
    float* __restrict__ Dp)
{
    __shared__ float Dl[4][32];
    int tid = threadIdx.x;
    int lane = tid & 63, w = tid >> 6;
    int l31 = lane & 31, h = lane >> 5;
    int b = blockIdx.y, z = blockIdx.z;
    int n0 = blockIdx.x * 32;

    f32x16 Z16;
    #pragma unroll
    for (int r = 0; r < 16; r++) Z16[r] = 0.0f;

    bf16x8 kf = zero8();
    if (lane < 32)
        kf = *(const bf16x8*)(KB + ((size_t)b*NN + n0 + l31)*8);

    float Dacc[16];
    #pragma unroll
    for (int r = 0; r < 16; r++) Dacc[r] = 0.0f;

    const __bf16* Qb = QB + (size_t)b*NN*8;
    int mbase = z*2304 + w*576;
    for (int it = 0; it < 18; it++) {
        bf16x8 qf = zero8();
        if (lane < 32)
            qf = *(const bf16x8*)(Qb + (size_t)(mbase + it*32 + l31)*8);
        f32x16 e = MFMA32(kf, qf, Z16);
        #pragma unroll
        for (int r = 0; r < 16; r++) Dacc[r] += EXP2(e[r]);
    }
    #pragma unroll
    for (int r = 0; r < 16; r++) {
        #pragma unroll
        for (int mask = 1; mask < 32; mask <<= 1)
            Dacc[r] += __shfl_xor(Dacc[r], mask);
    }
    if (l31 == 0) {
        #pragma unroll
        for (int r = 0; r < 16; r++)
            Dl[w][(r&3) + 8*(r>>2) + 4*h] = Dacc[r];
    }
    __syncthreads();
    if (tid < 32)
        Dp[((size_t)(z*2 + b))*NN + n0 + tid] =
            Dl[0][tid] + Dl[1][tid] + Dl[2][tid] + Dl[3][tid];
}

// ---------------- Kernel 3: build fragment-ordered folded VF ----------------
// grid (144, 2), block 256. Tile tg = 64 n. chunk = nt*4+ks*2+ct.
// VF element addr: ((b*144+tg)*8 + chunk)*512 + lane*8; holds
// V''[c = (chunk&1)*32 + (lane&31)][n0 + (chunk>>2)*32 + ((chunk>>1)&1)*16 + (lane>>5)*8 .. +7]
__global__ __launch_bounds__(256) void foldvf_kernel(
    const float* __restrict__ Dp, const float* __restrict__ gamma_p,
    const __bf16* __restrict__ VB, __bf16* __restrict__ VF)
{
    __shared__ float Rl[64];
    int tid = threadIdx.x;
    int b = blockIdx.y, tg = blockIdx.x;
    int n0 = tg * 64;
    if (tid < 64) {
        float d = 0.0f;
        #pragma unroll
        for (int zz = 0; zz < 4; zz++)
            d += Dp[((size_t)(zz*2 + b))*NN + n0 + tid];
        Rl[tid] = gamma_p[0] / d;
    }
    __syncthreads();

    #pragma unroll
    for (int i = 0; i < 2; i++) {
        int p = tid + i*256;               // 0..511
        int chunk = p >> 6, lane = p & 63;
        int c  = (chunk & 1)*32 + (lane & 31);
        int nl = ((chunk >> 2) & 1)*32 + ((chunk >> 1) & 1)*16 + (lane >> 5)*8;
        bf16x8 v = *(const bf16x8*)(VB + ((size_t)(b*64 + c))*NN + n0 + nl);
        bf16x8 ov;
        #pragma unroll
        for (int j = 0; j < 8; j++)
            ov[j] = (__bf16)((float)v[j] * Rl[nl + j]);
        *(bf16x8*)(VF + (((size_t)(b*144 + tg))*8 + chunk)*512 + lane*8) = ov;
    }
}

// ---------------- Kernel 4: out = x (atomic-fallback path only) ----------------
__global__ __launch_bounds__(256) void init_kernel(
    const float* __restrict__ x, float* __restrict__ out)
{
    int i = blockIdx.x*256 + threadIdx.x;
    ((float4*)out)[i] = ((const float4*)x)[i];
}

// ---------------- Kernel 5: fused exp2(E') + PV, LDS-staged fragment-ordered ----------------
// grid (72, 2, 8), block 256 (4 waves). Wave: 32 m. Split z: 1152 n, 18 tiles of 64.
// V staged per block (8KB/tile) from fragment-ordered VF; LDS reads are lane-stride-16B
// ds_read_b128 => 2-way bank aliasing = conflict-free. No swizzle anywhere.
__global__ __launch_bounds__(256) void pv_kernel(
    const __bf16* __restrict__ QB, const __bf16* __restrict__ KB,
    const __bf16* __restrict__ VF, float* __restrict__ out,
    __bf16* __restrict__ parts)
{
    __shared__ __bf16 vbuf[2][4096];   // 2 x 8KB fragment-ordered V tile
    __shared__ __bf16 klin[2][512];    // 2 x 1KB K tile

    int tid = threadIdx.x;
    int lane = tid & 63, w = tid >> 6;
    int l31 = lane & 31, h = lane >> 5;
    int b = blockIdx.y, s = blockIdx.z;
    int mw = blockIdx.x * 128 + w * 32;

    f32x16 Z16;
    #pragma unroll
    for (int r = 0; r < 16; r++) Z16[r] = 0.0f;

    bf16x8 qf = zero8();
    if (lane < 32)
        qf = *(const bf16x8*)(QB + ((size_t)b*NN + mw + l31)*8);

    f32x16 acc[2];
    acc[0] = Z16; acc[1] = Z16;

    const __bf16* kbase = KB + ((size_t)b*NN + s*1152)*8;       // + t*512 + row*8
    const __bf16* vbase = VF + ((size_t)(b*144 + s*18))*8*512;  // + t*4096 elements

// Linear both sides: thread p copies VF chunk-slot p (16B) to LDS offset p*16.
#define STAGE(bi, stq) do {                                                   \
    const __bf16* tile_ = vbase + (size_t)(stq)*4096;                         \
    cp16((char*)vbuf[bi] + w*1024,        tile_ + (w*64 + lane)*8);           \
    cp16((char*)vbuf[bi] + 4096 + w*1024, tile_ + (256 + w*64 + lane)*8);     \
    if (w == 0)                                                               \
        cp16((char*)klin[bi], kbase + ((size_t)(stq)*64 + lane)*8);           \
} while (0)

    STAGE(0, 0);

    for (int t = 0; t < 18; t++) {
        int bi = t & 1;
        __syncthreads();                  // stage(t) complete; buf[bi^1] free
        if (t < 17) {
            if (bi == 0) STAGE(1, t+1); else STAGE(0, t+1);
        }

        // QK: K fragments from LDS (half-wave b128 reads, conflict-free)
        bf16x8 kfr0 = zero8(), kfr1 = zero8();
        if (lane < 32) {
            kfr0 = *(const bf16x8*)(klin[bi] + l31*8);
            kfr1 = *(const bf16x8*)(klin[bi] + (32 + l31)*8);
        }
        f32x16 e0 = MFMA32(kfr0, qf, Z16);
        f32x16 e1 = MFMA32(kfr1, qf, Z16);

        // exp + pack into PV A-fragments (in-register, T12)
        bf16x8 pa[2][2];
        #pragma unroll
        for (int nt = 0; nt < 2; nt++) {
            const f32x16& e = nt ? e1 : e0;
            float pf[16];
            #pragma unroll
            for (int r = 0; r < 16; r++) pf[r] = EXP2(e[r]);
            unsigned int u[8];
            #pragma unroll
            for (int q = 0; q < 8; q++) u[q] = pk2(pf[2*q], pf[2*q+1]);
            plane_swap(u[0], u[2]); plane_swap(u[1], u[3]);
            plane_swap(u[4], u[6]); plane_swap(u[5], u[7]);
            u32x4 t0 = {u[0], u[1], u[2], u[3]};
            u32x4 t1 = {u[4], u[5], u[6], u[7]};
            pa[nt][0] = __builtin_bit_cast(bf16x8, t0);
            pa[nt][1] = __builtin_bit_cast(bf16x8, t1);
        }

        // PV cluster: chunk = nt*4 + ks*2 + ct; B-frag = ds_read_b128 at chunk*1KB + lane*16
        __builtin_amdgcn_s_setprio(1);
        #pragma unroll
        for (int chunk = 0; chunk < 8; chunk++) {
            bf16x8 bfr = *(const bf16x8*)((char*)vbuf[bi] + chunk*1024 + lane*16);
            acc[chunk & 1] = MFMA32(pa[chunk >> 2][(chunk >> 1) & 1], bfr, acc[chunk & 1]);
        }
        __builtin_amdgcn_s_setprio(0);
    }

    if (parts != nullptr) {
        __bf16* pp = parts + ((size_t)(s*2 + b))*64*NN;
        #pragma unroll
        for (int ct = 0; ct < 2; ct++) {
            int c = ct*32 + l31;
            __bf16* row = pp + (size_t)c*NN + mw + 4*h;
            #pragma unroll
            for (int q = 0; q < 4; q++) {
                uint2 v2;
                v2.x = pk2(acc[ct][4*q],   acc[ct][4*q+1]);
                v2.y = pk2(acc[ct][4*q+2], acc[ct][4*q+3]);
                *(uint2*)(row + q*8) = v2;
            }
        }
    } else {
        #pragma unroll
        for (int ct = 0; ct < 2; ct++) {
            int c = ct*32 + l31;
            #pragma unroll
            for (int r = 0; r < 16; r++) {
                int m = mw + (r&3) + 8*(r>>2) + 4*h;
                atomicAdd(out + ((size_t)(b*64 + c))*NN + m, (float)acc[ct][r]);
            }
        }
    }
}

// ---------------- Kernel 6: out = x + sum_s parts[s] ----------------
// grid 576, block 256; thread owns 8 consecutive floats (576*256*8 = 1179648 = out_size).
__global__ __launch_bounds__(256) void reduce_kernel(
    const float* __restrict__ x, const __bf16* __restrict__ parts,
    float* __restrict__ out)
{
    size_t f0 = ((size_t)blockIdx.x*256 + threadIdx.x) * 8;
    float o[8];
    float4 a = *(const float4*)(x + f0);
    float4 c = *(const float4*)(x + f0 + 4);
    o[0]=a.x; o[1]=a.y; o[2]=a.z; o[3]=a.w;
    o[4]=c.x; o[5]=c.y; o[6]=c.z; o[7]=c.w;
    #pragma unroll
    for (int sIdx = 0; sIdx < 8; sIdx++) {
        bf16x8 p = *(const bf16x8*)(parts + (size_t)sIdx*(128*NN) + f0);
        #pragma unroll
        for (int j = 0; j < 8; j++) o[j] += (float)p[j];
    }
    float4 r0 = make_float4(o[0],o[1],o[2],o[3]);
    float4 r1 = make_float4(o[4],o[5],o[6],o[7]);
    *(float4*)(out + f0) = r0;
    *(float4*)(out + f0 + 4) = r1;
}

extern "C" void kernel_launch(void* const* d_in, const int* in_sizes, int n_in,
                              void* d_out, int out_size, void* d_ws, size_t ws_size,
                              hipStream_t stream) {
    const float* x     = (const float*)d_in[0];
    const float* Wq    = (const float*)d_in[1];
    const float* bq    = (const float*)d_in[2];
    const float* Wk    = (const float*)d_in[3];
    const float* bk    = (const float*)d_in[4];
    const float* Wv    = (const float*)d_in[5];
    const float* bv    = (const float*)d_in[6];
    const float* gamma = (const float*)d_in[7];
    float* out = (float*)d_out;
    char* ws   = (char*)d_ws;

    __bf16* QB = (__bf16*)(ws + OFF_QB);
    __bf16* KB = (__bf16*)(ws + OFF_KB);
    __bf16* VB = (__bf16*)(ws + OFF_VB);
    __bf16* VF = (__bf16*)(ws + OFF_VF);
    float*  Dp = (float*)(ws + OFF_DP);

    qkv_kernel<<<dim3(36, 2, 9), 256, 0, stream>>>(x, Wq, bq, Wk, bk, Wv, bv, QB, KB, VB);
    stats_kernel<<<dim3(288, 2, 4), 256, 0, stream>>>(QB, KB, Dp);
    foldvf_kernel<<<dim3(144, 2), 256, 0, stream>>>(Dp, gamma, VB, VF);

    if (ws_size >= WS_NEED) {
        __bf16* parts = (__bf16*)(ws + OFF_PARTS);
        pv_kernel<<<dim3(72, 2, 8), 256, 0, stream>>>(QB, KB, VF, out, parts);
        reduce_kernel<<<dim3(576), 256, 0, stream>>>(x, parts, out);
    } else {
        init_kernel<<<dim3(1152), 256, 0, stream>>>(x, out);
        pv_kernel<<<dim3(72, 2, 8), 256, 0, stream>>>(QB, KB, VF, out, nullptr);
    }
}

// Round 9
// 100.633 us; speedup vs baseline: 1.1060x; 1.0066x over previous
//
#include <hip/hip_runtime.h>
#include <math.h>

#define NN 9216           // 96*96
#define LOG2E 1.4426950408889634f

typedef __attribute__((ext_vector_type(8))) __bf16 bf16x8;
typedef __attribute__((ext_vector_type(16))) float f32x16;
typedef __attribute__((ext_vector_type(4))) unsigned int u32x4;

#define MFMA32(a,b,c) __builtin_amdgcn_mfma_f32_32x32x16_bf16(a,b,c,0,0,0)

#if __has_builtin(__builtin_amdgcn_exp2f)
#define EXP2(x) __builtin_amdgcn_exp2f(x)
#else
#define EXP2(x) exp2f(x)
#endif

__device__ __forceinline__ bf16x8 zero8() {
    bf16x8 z;
    #pragma unroll
    for (int i = 0; i < 8; i++) z[i] = (__bf16)0.0f;
    return z;
}

__device__ __forceinline__ unsigned int pk2(float a, float b) {
    unsigned short ua = __builtin_bit_cast(unsigned short, (__bf16)a);
    unsigned short ub = __builtin_bit_cast(unsigned short, (__bf16)b);
    return (unsigned int)ua | ((unsigned int)ub << 16);
}

__device__ __forceinline__ void plane_swap(unsigned int &a, unsigned int &b) {
    asm("v_permlane32_swap_b32 %0, %1" : "+v"(a), "+v"(b));
}

__device__ __forceinline__ void cp16(void* lds, const void* g) {
    __builtin_amdgcn_global_load_lds(
        (const __attribute__((address_space(1))) unsigned int*)g,
        (__attribute__((address_space(3))) unsigned int*)lds, 16, 0, 0);
}

// Workspace layout (bytes):
#define OFF_QB 0              // [B][N][8]  bf16 (Q pre-scaled by log2e)
#define OFF_KB 294912         // [B][N][8]  bf16
#define OFF_VB 589824         // [B][64][N] bf16 (raw V, unfolded)
#define OFF_VF 2949120        // [B][144 tiles][8 chunks][64 lanes][8] bf16, fragment-ordered folded V
#define OFF_DP 5308416        // [4z][2b][N] fp32 D-partials
#define OFF_PARTS 5308416     // [12][B][64][N] bf16 PV partials (aliases Dp; Dp dead before pv)
#define WS_NEED 33619968ULL

// ---------------- Kernel 1: QKV projections ----------------
// grid (36, 2, 9), block 256. z==0: Q,K. z=1..8: V channels (z-1)*8..+8.
__global__ __launch_bounds__(256) void qkv_kernel(
    const float* __restrict__ x,
    const float* __restrict__ Wq, const float* __restrict__ bq,
    const float* __restrict__ Wk, const float* __restrict__ bk,
    const float* __restrict__ Wv, const float* __restrict__ bv,
    __bf16* __restrict__ QB, __bf16* __restrict__ KB, __bf16* __restrict__ VB)
{
    __shared__ float wsh[1024], bsh[16];
    int tid = threadIdx.x;
    int z = blockIdx.z, b = blockIdx.y;
    if (z == 0) {
        for (int i = tid; i < 512; i += 256) { wsh[i] = Wq[i]; wsh[512+i] = Wk[i]; }
        if (tid < 8)  { bsh[tid] = bq[tid]; bsh[8+tid] = bk[tid]; }
    } else {
        for (int i = tid; i < 512; i += 256) wsh[i] = Wv[(z-1)*512 + i];
        if (tid < 8)  bsh[tid] = bv[(z-1)*8 + tid];
    }
    __syncthreads();

    int n = blockIdx.x * 256 + tid;

    float xc[64];
    #pragma unroll
    for (int c = 0; c < 64; c++) xc[c] = x[((size_t)(b*64 + c))*NN + n];

    if (z == 0) {
        float q[8], k[8];
        #pragma unroll
        for (int o = 0; o < 8; o++) { q[o] = bsh[o]; k[o] = bsh[8+o]; }
        #pragma unroll
        for (int c = 0; c < 64; c++) {
            float xv = xc[c];
            #pragma unroll
            for (int o = 0; o < 8; o++) {
                q[o] = fmaf(wsh[o*64+c], xv, q[o]);
                k[o] = fmaf(wsh[512+o*64+c], xv, k[o]);
            }
        }
        bf16x8 qv, kv;
        #pragma unroll
        for (int o = 0; o < 8; o++) {
            qv[o] = (__bf16)(q[o] * LOG2E);   // fold log2e: exp(E)=exp2(E')
            kv[o] = (__bf16)k[o];
        }
        *(bf16x8*)(QB + ((size_t)b*NN + n)*8) = qv;
        *(bf16x8*)(KB + ((size_t)b*NN + n)*8) = kv;
    } else {
        float v[8];
        #pragma unroll
        for (int o = 0; o < 8; o++) v[o] = bsh[o];
        #pragma unroll
        for (int c = 0; c < 64; c++) {
            float xv = xc[c];
            #pragma unroll
            for (int o = 0; o < 8; o++) v[o] = fmaf(wsh[o*64+c], xv, v[o]);
        }
        #pragma unroll
        for (int o = 0; o < 8; o++)
            VB[((size_t)(b*64 + (z-1)*8 + o))*NN + n] = (__bf16)v[o];
    }
}

// ---------------- Kernel 2: D-partials via 32x32x16 MFMA ----------------
// grid (288, 2, 4), block 256 (4 waves). Block owns 32 n; z+wave split m 16 ways.
__global__ __launch_bounds__(256) void stats_kernel(
    const __bf16* __restrict__ QB, const __bf16* __restrict__ KB,
    float* __restrict__ Dp)
{
    __shared__ float Dl[4][32];
    int tid = threadIdx.x;
    int lane = tid & 63, w = tid >> 6;
    int l31 = lane & 31, h = lane >> 5;
    int b = blockIdx.y, z = blockIdx.z;
    int n0 = blockIdx.x * 32;

    f32x16 Z16;
    #pragma unroll
    for (int r = 0; r < 16; r++) Z16[r] = 0.0f;

    bf16x8 kf = zero8();
    if (lane < 32)
        kf = *(const bf16x8*)(KB + ((size_t)b*NN + n0 + l31)*8);

    float Dacc[16];
    #pragma unroll
    for (int r = 0; r < 16; r++) Dacc[r] = 0.0f;

    const __bf16* Qb = QB + (size_t)b*NN*8;
    int mbase = z*2304 + w*576;
    for (int it = 0; it < 18; it++) {
        bf16x8 qf = zero8();
        if (lane < 32)
            qf = *(const bf16x8*)(Qb + (size_t)(mbase + it*32 + l31)*8);
        f32x16 e = MFMA32(kf, qf, Z16);
        #pragma unroll
        for (int r = 0; r < 16; r++) Dacc[r] += EXP2(e[r]);
    }
    #pragma unroll
    for (int r = 0; r < 16; r++) {
        #pragma unroll
        for (int mask = 1; mask < 32; mask <<= 1)
            Dacc[r] += __shfl_xor(Dacc[r], mask);
    }
    if (l31 == 0) {
        #pragma unroll
        for (int r = 0; r < 16; r++)
            Dl[w][(r&3) + 8*(r>>2) + 4*h] = Dacc[r];
    }
    __syncthreads();
    if (tid < 32)
        Dp[((size_t)(z*2 + b))*NN + n0 + tid] =
            Dl[0][tid] + Dl[1][tid] + Dl[2][tid] + Dl[3][tid];
}

// ---------------- Kernel 3: build fragment-ordered folded VF ----------------
// grid (144, 2), block 256. Tile tg = 64 n. chunk = nt*4+ks*2+ct.
// VF element addr: ((b*144+tg)*8 + chunk)*512 + lane*8; holds
// V''[c = (chunk&1)*32 + (lane&31)][n0 + (chunk>>2)*32 + ((chunk>>1)&1)*16 + (lane>>5)*8 .. +7]
__global__ __launch_bounds__(256) void foldvf_kernel(
    const float* __restrict__ Dp, const float* __restrict__ gamma_p,
    const __bf16* __restrict__ VB, __bf16* __restrict__ VF)
{
    __shared__ float Rl[64];
    int tid = threadIdx.x;
    int b = blockIdx.y, tg = blockIdx.x;
    int n0 = tg * 64;
    if (tid < 64) {
        float d = 0.0f;
        #pragma unroll
        for (int zz = 0; zz < 4; zz++)
            d += Dp[((size_t)(zz*2 + b))*NN + n0 + tid];
        Rl[tid] = gamma_p[0] / d;
    }
    __syncthreads();

    #pragma unroll
    for (int i = 0; i < 2; i++) {
        int p = tid + i*256;               // 0..511
        int chunk = p >> 6, lane = p & 63;
        int c  = (chunk & 1)*32 + (lane & 31);
        int nl = ((chunk >> 2) & 1)*32 + ((chunk >> 1) & 1)*16 + (lane >> 5)*8;
        bf16x8 v = *(const bf16x8*)(VB + ((size_t)(b*64 + c))*NN + n0 + nl);
        bf16x8 ov;
        #pragma unroll
        for (int j = 0; j < 8; j++)
            ov[j] = (__bf16)((float)v[j] * Rl[nl + j]);
        *(bf16x8*)(VF + (((size_t)(b*144 + tg))*8 + chunk)*512 + lane*8) = ov;
    }
}

// ---------------- Kernel 4: out = x (atomic-fallback path only) ----------------
__global__ __launch_bounds__(256) void init_kernel(
    const float* __restrict__ x, float* __restrict__ out)
{
    int i = blockIdx.x*256 + threadIdx.x;
    ((float4*)out)[i] = ((const float4*)x)[i];
}

// ---------------- Kernel 5: fused exp2(E') + PV, LDS-staged fragment-ordered ----------------
// grid (72, 2, 12), block 256 (4 waves). Wave: 32 m. Split z: 768 n, 12 tiles of 64.
// V staged per block (8KB/tile) from fragment-ordered VF; LDS reads are lane-stride-16B
// ds_read_b128 => 2-way bank aliasing = conflict-free. No swizzle anywhere.
__global__ __launch_bounds__(256) void pv_kernel(
    const __bf16* __restrict__ QB, const __bf16* __restrict__ KB,
    const __bf16* __restrict__ VF, float* __restrict__ out,
    __bf16* __restrict__ parts)
{
    __shared__ __bf16 vbuf[2][4096];   // 2 x 8KB fragment-ordered V tile
    __shared__ __bf16 klin[2][512];    // 2 x 1KB K tile

    int tid = threadIdx.x;
    int lane = tid & 63, w = tid >> 6;
    int l31 = lane & 31, h = lane >> 5;
    int b = blockIdx.y, s = blockIdx.z;
    int mw = blockIdx.x * 128 + w * 32;

    f32x16 Z16;
    #pragma unroll
    for (int r = 0; r < 16; r++) Z16[r] = 0.0f;

    bf16x8 qf = zero8();
    if (lane < 32)
        qf = *(const bf16x8*)(QB + ((size_t)b*NN + mw + l31)*8);

    f32x16 acc[2];
    acc[0] = Z16; acc[1] = Z16;

    const __bf16* kbase = KB + ((size_t)b*NN + s*768)*8;        // + t*512 + row*8
    const __bf16* vbase = VF + ((size_t)(b*144 + s*12))*8*512;  // + t*4096 elements

// Linear both sides: thread p copies VF chunk-slot p (16B) to LDS offset p*16.
#define STAGE(bi, stq) do {                                                   \
    const __bf16* tile_ = vbase + (size_t)(stq)*4096;                         \
    cp16((char*)vbuf[bi] + w*1024,        tile_ + (w*64 + lane)*8);           \
    cp16((char*)vbuf[bi] + 4096 + w*1024, tile_ + (256 + w*64 + lane)*8);     \
    if (w == 0)                                                               \
        cp16((char*)klin[bi], kbase + ((size_t)(stq)*64 + lane)*8);           \
} while (0)

    STAGE(0, 0);

    for (int t = 0; t < 12; t++) {
        int bi = t & 1;
        __syncthreads();                  // stage(t) complete; buf[bi^1] free
        if (t < 11) {
            if (bi == 0) STAGE(1, t+1); else STAGE(0, t+1);
        }

        // QK: K fragments from LDS (half-wave b128 reads, conflict-free)
        bf16x8 kfr0 = zero8(), kfr1 = zero8();
        if (lane < 32) {
            kfr0 = *(const bf16x8*)(klin[bi] + l31*8);
            kfr1 = *(const bf16x8*)(klin[bi] + (32 + l31)*8);
        }
        f32x16 e0 = MFMA32(kfr0, qf, Z16);
        f32x16 e1 = MFMA32(kfr1, qf, Z16);

        // exp + pack into PV A-fragments (in-register, T12)
        bf16x8 pa[2][2];
        #pragma unroll
        for (int nt = 0; nt < 2; nt++) {
            const f32x16& e = nt ? e1 : e0;
            float pf[16];
            #pragma unroll
            for (int r = 0; r < 16; r++) pf[r] = EXP2(e[r]);
            unsigned int u[8];
            #pragma unroll
            for (int q = 0; q < 8; q++) u[q] = pk2(pf[2*q], pf[2*q+1]);
            plane_swap(u[0], u[2]); plane_swap(u[1], u[3]);
            plane_swap(u[4], u[6]); plane_swap(u[5], u[7]);
            u32x4 t0 = {u[0], u[1], u[2], u[3]};
            u32x4 t1 = {u[4], u[5], u[6], u[7]};
            pa[nt][0] = __builtin_bit_cast(bf16x8, t0);
            pa[nt][1] = __builtin_bit_cast(bf16x8, t1);
        }

        // PV cluster: chunk = nt*4 + ks*2 + ct; B-frag = ds_read_b128 at chunk*1KB + lane*16
        __builtin_amdgcn_s_setprio(1);
        #pragma unroll
        for (int chunk = 0; chunk < 8; chunk++) {
            bf16x8 bfr = *(const bf16x8*)((char*)vbuf[bi] + chunk*1024 + lane*16);
            acc[chunk & 1] = MFMA32(pa[chunk >> 2][(chunk >> 1) & 1], bfr, acc[chunk & 1]);
        }
        __builtin_amdgcn_s_setprio(0);
    }

    if (parts != nullptr) {
        __bf16* pp = parts + ((size_t)(s*2 + b))*64*NN;
        #pragma unroll
        for (int ct = 0; ct < 2; ct++) {
            int c = ct*32 + l31;
            __bf16* row = pp + (size_t)c*NN + mw + 4*h;
            #pragma unroll
            for (int q = 0; q < 4; q++) {
                uint2 v2;
                v2.x = pk2(acc[ct][4*q],   acc[ct][4*q+1]);
                v2.y = pk2(acc[ct][4*q+2], acc[ct][4*q+3]);
                *(uint2*)(row + q*8) = v2;
            }
        }
    } else {
        #pragma unroll
        for (int ct = 0; ct < 2; ct++) {
            int c = ct*32 + l31;
            #pragma unroll
            for (int r = 0; r < 16; r++) {
                int m = mw + (r&3) + 8*(r>>2) + 4*h;
                atomicAdd(out + ((size_t)(b*64 + c))*NN + m, (float)acc[ct][r]);
            }
        }
    }
}

// ---------------- Kernel 6: out = x + sum_s parts[s] ----------------
// grid 576, block 256; thread owns 8 consecutive floats (576*256*8 = 1179648 = out_size).
__global__ __launch_bounds__(256) void reduce_kernel(
    const float* __restrict__ x, const __bf16* __restrict__ parts,
    float* __restrict__ out)
{
    size_t f0 = ((size_t)blockIdx.x*256 + threadIdx.x) * 8;
    float o[8];
    float4 a = *(const float4*)(x + f0);
    float4 c = *(const float4*)(x + f0 + 4);
    o[0]=a.x; o[1]=a.y; o[2]=a.z; o[3]=a.w;
    o[4]=c.x; o[5]=c.y; o[6]=c.z; o[7]=c.w;
    #pragma unroll
    for (int sIdx = 0; sIdx < 12; sIdx++) {
        bf16x8 p = *(const bf16x8*)(parts + (size_t)sIdx*(128*NN) + f0);
        #pragma unroll
        for (int j = 0; j < 8; j++) o[j] += (float)p[j];
    }
    float4 r0 = make_float4(o[0],o[1],o[2],o[3]);
    float4 r1 = make_float4(o[4],o[5],o[6],o[7]);
    *(float4*)(out + f0) = r0;
    *(float4*)(out + f0 + 4) = r1;
}

extern "C" void kernel_launch(void* const* d_in, const int* in_sizes, int n_in,
                              void* d_out, int out_size, void* d_ws, size_t ws_size,
                              hipStream_t stream) {
    const float* x     = (const float*)d_in[0];
    const float* Wq    = (const float*)d_in[1];
    const float* bq    = (const float*)d_in[2];
    const float* Wk    = (const float*)d_in[3];
    const float* bk    = (const float*)d_in[4];
    const float* Wv    = (const float*)d_in[5];
    const float* bv    = (const float*)d_in[6];
    const float* gamma = (const float*)d_in[7];
    float* out = (float*)d_out;
    char* ws   = (char*)d_ws;

    __bf16* QB = (__bf16*)(ws + OFF_QB);
    __bf16* KB = (__bf16*)(ws + OFF_KB);
    __bf16* VB = (__bf16*)(ws + OFF_VB);
    __bf16* VF = (__bf16*)(ws + OFF_VF);
    float*  Dp = (float*)(ws + OFF_DP);

    qkv_kernel<<<dim3(36, 2, 9), 256, 0, stream>>>(x, Wq, bq, Wk, bk, Wv, bv, QB, KB, VB);
    stats_kernel<<<dim3(288, 2, 4), 256, 0, stream>>>(QB, KB, Dp);
    foldvf_kernel<<<dim3(144, 2), 256, 0, stream>>>(Dp, gamma, VB, VF);

    if (ws_size >= WS_NEED) {
        __bf16* parts = (__bf16*)(ws + OFF_PARTS);
        pv_kernel<<<dim3(72, 2, 12), 256, 0, stream>>>(QB, KB, VF, out, parts);
        reduce_kernel<<<dim3(576), 256, 0, stream>>>(x, parts, out);
    } else {
        init_kernel<<<dim3(1152), 256, 0, stream>>>(x, out);
        pv_kernel<<<dim3(72, 2, 12), 256, 0, stream>>>(QB, KB, VF, out, nullptr);
    }
}